// Round 6
// baseline (2857.418 us; speedup 1.0000x reference)
//
#include <hip/hip_runtime.h>
#include <hip/hip_bf16.h>

#define NN 30000
#define NE 480000
#define ADL 2.8332133440562162f   // ln(17)

typedef unsigned int u32;

// ======================= CSR build =======================
__global__ void k_zero(int* __restrict__ cnt, int* __restrict__ cursor){
  int i = blockIdx.x * blockDim.x + threadIdx.x;
  if (i < NN){ cnt[i] = 0; cursor[i] = 0; }
}

__global__ void k_hist(const int* __restrict__ ei, int* __restrict__ cnt){
  int e = blockIdx.x * blockDim.x + threadIdx.x;
  if (e < NE) atomicAdd(&cnt[ei[NE + e]], 1);
}

__global__ __launch_bounds__(1024) void k_scan(const int* __restrict__ cnt, int* __restrict__ off){
  __shared__ int buf[1024];
  __shared__ int s_carry;
  const int tid = threadIdx.x;
  if (tid == 0) s_carry = 0;
  __syncthreads();
  for (int base = 0; base < NN; base += 1024){
    int i = base + tid;
    int v = (i < NN) ? cnt[i] : 0;
    buf[tid] = v;
    __syncthreads();
    for (int s = 1; s < 1024; s <<= 1){
      int t = (tid >= s) ? buf[tid - s] : 0;
      __syncthreads();
      buf[tid] += t;
      __syncthreads();
    }
    int carry = s_carry;
    if (i < NN) off[i] = carry + buf[tid] - v;
    __syncthreads();
    if (tid == 0) s_carry = carry + buf[1023];
    __syncthreads();
  }
  if (tid == 0) off[NN] = s_carry;
}

__global__ void k_scatter(const int* __restrict__ ei, const int* __restrict__ off,
                          int* __restrict__ cursor, int* __restrict__ eids){
  int e = blockIdx.x * blockDim.x + threadIdx.x;
  if (e < NE){
    int d = ei[NE + e];
    int pos = off[d] + atomicAdd(&cursor[d], 1);
    eids[pos] = e;
  }
}

// ======================= weight transposes (f32 -> f32, [c][k]) =======================
__global__ void k_prep(const float* __restrict__ preW0, const float* __restrict__ preW1,
                       const float* __restrict__ postW0, const float* __restrict__ postW1,
                       const float* __restrict__ Wlin,
                       float* __restrict__ preW0T, float* __restrict__ preW1T,
                       float* __restrict__ postW0T, float* __restrict__ postW1T,
                       float* __restrict__ WlinT)
{
  int i = blockIdx.x * blockDim.x + threadIdx.x;
  if (i < 65536){ int c = i >> 9, kk = i & 511;
    postW0T[i] = postW0[(c >> 5)*16384 + kk*32 + (c & 31)]; }
  if (i < 12288){ int c = i / 96, k = i % 96;
    preW0T[i] = preW0[(c >> 5)*3072 + k*32 + (c & 31)]; }
  if (i < 4096){ int c = i >> 5, g = i & 31;
    preW1T[i]  = preW1[(c >> 5)*1024 + g*32 + (c & 31)];
    postW1T[i] = postW1[(c >> 5)*1024 + g*32 + (c & 31)]; }
  if (i < 16384){ int c = i >> 7, k = i & 127; WlinT[i] = Wlin[k*128 + c]; }
}

// ======================= ea precompute, CSR-ordered =======================
__global__ __launch_bounds__(256) void k_ea(const float* __restrict__ eattr,
                                            const float* __restrict__ Wedge,
                                            const float* __restrict__ b_edge,
                                            const int* __restrict__ eids,
                                            float* __restrict__ eaC)
{
  __shared__ float WS[512];
  __shared__ float bS[32];
  const int tid = threadIdx.x;
  WS[tid]       = Wedge[tid];
  WS[tid + 256] = Wedge[tid + 256];
  if (tid < 32) bS[tid] = b_edge[tid];
  __syncthreads();
  const int g = tid & 31;
  const int pos = blockIdx.x * 8 + (tid >> 5);
  if (pos < NE){
    const int e = eids[pos];
    const float* ar = eattr + (size_t)e * 16;
    float acc = bS[g];
    #pragma unroll
    for (int ii = 0; ii < 16; ++ii) acc = fmaf(ar[ii], WS[ii*32 + g], acc);
    eaC[(size_t)pos*32 + g] = acc;
  }
}

// ======================= edge phase v2: lane=edge, wave=tower, SGPR weights =======================
// Block = 256 threads = 4 waves; wave t handles tower t for a window of 64 CSR-ordered edges.
// Activations (96 floats) live in per-lane VGPRs; weights are wave-uniform scalar loads.
// Messages go to LDS hm[64][133] (133 = conflict-free stride); threads 0..127 (=channels)
// run a segmented CSR scan per window, carrying per-node {sum,sq,min,max} across windows.
__global__ __launch_bounds__(256, 4) void k_edge2(
  const float* __restrict__ x, const int* __restrict__ ei,
  const float* __restrict__ eaC,
  const float* __restrict__ preW0T, const float* __restrict__ preW1,
  const float* __restrict__ pre_b0, const float* __restrict__ pre_b1,
  const int* __restrict__ off, const int* __restrict__ eids,
  float* __restrict__ agg)
{
  const int tid  = threadIdx.x;
  const int lane = tid & 63;
  const int t    = __builtin_amdgcn_readfirstlane(tid >> 6);   // tower, provably wave-uniform
  const int n0   = blockIdx.x * 8;

  __shared__ float hm[64][133];
  __shared__ int offS[9];
  __shared__ int sidS[64];

  if (tid < 9) offS[tid] = off[n0 + tid];
  __syncthreads();
  const int e0 = offS[0], e1 = offS[8];

  // scan state (threads 0..127 only)
  float s_sum = 0.f, s_sq = 0.f;
  float s_mn = __builtin_inff(), s_mx = -__builtin_inff();
  int cur = 0;

  for (int base = e0; base < e1; base += 64){
    const int nv = min(64, e1 - base);
    if (tid < nv) sidS[tid] = ei[eids[base + tid]];
    __syncthreads();

    // ---------- compute phase: one edge per lane ----------
    {
      const int jl  = (lane < nv) ? lane : 0;
      const int pos = base + jl;
      // dst node: branchless rank within the block's 8-node offset table
      int d = 0;
      #pragma unroll
      for (int q = 0; q < 8; ++q) d += (pos >= offS[q+1]) ? 1 : 0;
      const int dn = n0 + d;
      const int sn = sidS[jl];

      float4 A[24];
      const float* xdp = x + (size_t)dn*128 + t*32;
      const float* xsp = x + (size_t)sn*128 + t*32;
      const float* eap = eaC + (size_t)pos*32;
      #pragma unroll
      for (int q = 0; q < 8; ++q) A[q]      = *(const float4*)(xdp + q*4);
      #pragma unroll
      for (int q = 0; q < 8; ++q) A[8 + q]  = *(const float4*)(xsp + q*4);
      #pragma unroll
      for (int q = 0; q < 8; ++q) A[16 + q] = *(const float4*)(eap + q*4);

      // layer0: g rolled (wave-uniform weight rows -> s_load), h -> LDS
      for (int g = 0; g < 32; ++g){
        const float* Wg = preW0T + (size_t)(t*32 + g)*96;
        float acc = pre_b0[t*32 + g];
        #pragma unroll
        for (int q = 0; q < 24; ++q){
          acc = fmaf(A[q].x, Wg[q*4+0], acc);
          acc = fmaf(A[q].y, Wg[q*4+1], acc);
          acc = fmaf(A[q].z, Wg[q*4+2], acc);
          acc = fmaf(A[q].w, Wg[q*4+3], acc);
        }
        hm[lane][t*32 + g] = fmaxf(acc, 0.f);
      }

      // layer1: m[f] accumulated in regs (f static via unroll), then overwrite hm with m
      float m[32];
      #pragma unroll
      for (int f = 0; f < 32; ++f) m[f] = pre_b1[t*32 + f];
      for (int g = 0; g < 32; ++g){
        const float hg = hm[lane][t*32 + g];
        const float* W1g = preW1 + t*1024 + g*32;   // original [t][g][f] layout: f contiguous
        #pragma unroll
        for (int f = 0; f < 32; ++f) m[f] = fmaf(hg, W1g[f], m[f]);
      }
      #pragma unroll
      for (int f = 0; f < 32; ++f) hm[lane][t*32 + f] = m[f];
    }
    __syncthreads();

    // ---------- scan phase: thread = channel, serial over window edges ----------
    if (tid < 128){
      for (int j = 0; j < nv; ++j){
        const int gpos = base + j;
        while (gpos >= offS[cur + 1]){
          const int deg = offS[cur + 1] - offS[cur];
          const size_t b = (size_t)(n0 + cur) * 512;
          agg[b + tid]       = s_sum;
          agg[b + 128 + tid] = s_sq;
          agg[b + 256 + tid] = (deg > 0) ? s_mn : 0.f;
          agg[b + 384 + tid] = (deg > 0) ? s_mx : 0.f;
          s_sum = 0.f; s_sq = 0.f;
          s_mn = __builtin_inff(); s_mx = -__builtin_inff();
          ++cur;
        }
        const float mv = hm[j][tid];
        s_sum += mv; s_sq = fmaf(mv, mv, s_sq);
        s_mn = fminf(s_mn, mv); s_mx = fmaxf(s_mx, mv);
      }
    }
    __syncthreads();
  }

  // final flush: remaining nodes (including degree-0)
  if (tid < 128){
    while (cur < 8){
      const int deg = offS[cur + 1] - offS[cur];
      const size_t b = (size_t)(n0 + cur) * 512;
      agg[b + tid]       = s_sum;
      agg[b + 128 + tid] = s_sq;
      agg[b + 256 + tid] = (deg > 0) ? s_mn : 0.f;
      agg[b + 384 + tid] = (deg > 0) ? s_mx : 0.f;
      s_sum = 0.f; s_sq = 0.f;
      s_mn = __builtin_inff(); s_mx = -__builtin_inff();
      ++cur;
    }
  }
}

// ======================= node phase: G=12 nodes/block, register-tiled =======================
__global__ __launch_bounds__(128, 2) void k_post(
  const float* __restrict__ x, const float* __restrict__ agg,
  const int* __restrict__ off,
  const float* __restrict__ postW0T, const float* __restrict__ postW1T,
  const float* __restrict__ WlinT,
  const float* __restrict__ post_b0, const float* __restrict__ post_b1,
  const float* __restrict__ b_lin, const float* __restrict__ ln_g,
  const float* __restrict__ ln_b,
  float* __restrict__ out)
{
  const int c = threadIdx.x;
  const int t = c >> 5;
  const int n0 = blockIdx.x * 12;

  __shared__ __align__(16) float aS[12][768];   // [xd | sum | mean | mn | mx | std] x 128
  __shared__ __align__(16) float hpS[12][128];
  __shared__ __align__(16) float vS[12][128];
  __shared__ float s1S[12], s2S[12], muS[12], rsS[12];

  #pragma unroll
  for (int n = 0; n < 12; ++n){
    const size_t nb = (size_t)(n0 + n);
    aS[n][c] = x[nb*128 + c];
    float sum = agg[nb*512 + c];
    float sq  = agg[nb*512 + 128 + c];
    float mnv = agg[nb*512 + 256 + c];
    float mxv = agg[nb*512 + 384 + c];
    int deg = off[n0+n+1] - off[n0+n];
    float denom = fmaxf((float)deg, 1.f);
    float mean = sum / denom;
    float sd = sqrtf(fmaxf(sq/denom - mean*mean, 0.f) + 1e-5f);
    aS[n][128 + c] = sum;  aS[n][256 + c] = mean;
    aS[n][384 + c] = mnv;  aS[n][512 + c] = mxv;  aS[n][640 + c] = sd;
  }
  if (c < 12){
    int deg = off[n0+c+1] - off[n0+c];
    float logd = logf(fmaxf((float)deg, 1.f) + 1.f);
    s1S[c] = logd / ADL; s2S[c] = ADL / logd;
  }
  __syncthreads();

  float acc[12], pa1[12], pa2[12];
  const float pb0 = post_b0[c];
  #pragma unroll
  for (int n = 0; n < 12; ++n){ acc[n] = pb0; pa1[n] = 0.f; pa2[n] = 0.f; }
  const float* Wp = postW0T + (size_t)c * 512;
  #pragma unroll
  for (int k4 = 0; k4 < 8; ++k4){
    float4 w = *(const float4*)(Wp + k4*4);
    #pragma unroll
    for (int n = 0; n < 12; ++n){
      float4 a = *(const float4*)&aS[n][t*32 + k4*4];
      acc[n] = fmaf(a.x, w.x, acc[n]); acc[n] = fmaf(a.y, w.y, acc[n]);
      acc[n] = fmaf(a.z, w.z, acc[n]); acc[n] = fmaf(a.w, w.w, acc[n]);
    }
  }
  for (int a = 0; a < 5; ++a){
    #pragma unroll
    for (int k4 = 0; k4 < 8; ++k4){
      float4 w0v = *(const float4*)(Wp + 32  + a*32 + k4*4);
      float4 w1v = *(const float4*)(Wp + 192 + a*32 + k4*4);
      float4 w2v = *(const float4*)(Wp + 352 + a*32 + k4*4);
      #pragma unroll
      for (int n = 0; n < 12; ++n){
        float4 av = *(const float4*)&aS[n][128 + a*128 + t*32 + k4*4];
        acc[n] = fmaf(av.x, w0v.x, acc[n]); acc[n] = fmaf(av.y, w0v.y, acc[n]);
        acc[n] = fmaf(av.z, w0v.z, acc[n]); acc[n] = fmaf(av.w, w0v.w, acc[n]);
        pa1[n] = fmaf(av.x, w1v.x, pa1[n]); pa1[n] = fmaf(av.y, w1v.y, pa1[n]);
        pa1[n] = fmaf(av.z, w1v.z, pa1[n]); pa1[n] = fmaf(av.w, w1v.w, pa1[n]);
        pa2[n] = fmaf(av.x, w2v.x, pa2[n]); pa2[n] = fmaf(av.y, w2v.y, pa2[n]);
        pa2[n] = fmaf(av.z, w2v.z, pa2[n]); pa2[n] = fmaf(av.w, w2v.w, pa2[n]);
      }
    }
  }
  #pragma unroll
  for (int n = 0; n < 12; ++n)
    hpS[n][c] = fmaxf(acc[n] + s1S[n]*pa1[n] + s2S[n]*pa2[n], 0.f);
  __syncthreads();

  float w1r[32];
  #pragma unroll
  for (int q = 0; q < 8; ++q) *(float4*)&w1r[q*4] = *(const float4*)(postW1T + (size_t)c*32 + q*4);
  float a2[12];
  const float pb1v = post_b1[c];
  #pragma unroll
  for (int n = 0; n < 12; ++n) a2[n] = pb1v;
  #pragma unroll
  for (int g4 = 0; g4 < 8; ++g4){
    #pragma unroll
    for (int n = 0; n < 12; ++n){
      float4 h = *(const float4*)&hpS[n][t*32 + g4*4];
      a2[n] = fmaf(h.x, w1r[g4*4+0], a2[n]); a2[n] = fmaf(h.y, w1r[g4*4+1], a2[n]);
      a2[n] = fmaf(h.z, w1r[g4*4+2], a2[n]); a2[n] = fmaf(h.w, w1r[g4*4+3], a2[n]);
    }
  }
  #pragma unroll
  for (int n = 0; n < 12; ++n) vS[n][c] = a2[n];
  __syncthreads();

  float a3[12];
  const float blv = b_lin[c];
  #pragma unroll
  for (int n = 0; n < 12; ++n) a3[n] = blv;
  const float* Wl = WlinT + (size_t)c * 128;
  #pragma unroll 8
  for (int k4 = 0; k4 < 32; ++k4){
    float4 w = *(const float4*)(Wl + k4*4);
    #pragma unroll
    for (int n = 0; n < 12; ++n){
      float4 v = *(const float4*)&vS[n][k4*4];
      a3[n] = fmaf(v.x, w.x, a3[n]); a3[n] = fmaf(v.y, w.y, a3[n]);
      a3[n] = fmaf(v.z, w.z, a3[n]); a3[n] = fmaf(v.w, w.w, a3[n]);
    }
  }

  #pragma unroll
  for (int n = 0; n < 12; ++n) hpS[n][c] = a3[n];
  __syncthreads();
  {
    const int n = c >> 3, seg = c & 7;
    if (n < 12){
      float ps = 0.f, ps2 = 0.f;
      #pragma unroll
      for (int k = 0; k < 16; ++k){
        float v = hpS[n][seg*16 + k];
        ps += v; ps2 = fmaf(v, v, ps2);
      }
      ps += __shfl_xor(ps, 1); ps2 += __shfl_xor(ps2, 1);
      ps += __shfl_xor(ps, 2); ps2 += __shfl_xor(ps2, 2);
      ps += __shfl_xor(ps, 4); ps2 += __shfl_xor(ps2, 4);
      if (seg == 0){
        float mu = ps * (1.f/128.f);
        float var = fmaxf(ps2 * (1.f/128.f) - mu*mu, 0.f);
        muS[n] = mu; rsS[n] = rsqrtf(var + 1e-5f);
      }
    }
  }
  __syncthreads();
  const float gv = ln_g[c], bv = ln_b[c];
  #pragma unroll
  for (int n = 0; n < 12; ++n){
    float o = aS[n][c] + fmaxf((a3[n] - muS[n])*rsS[n]*gv + bv, 0.f);
    out[(size_t)(n0 + n)*128 + c] = o;
  }
}

// ======================= fallback: proven monolithic kernel (R3, f32) =======================
__global__ __launch_bounds__(128) void k_mono(
  const float* __restrict__ x, const int* __restrict__ ei,
  const float* __restrict__ eattr,
  const float* __restrict__ Wedge, const float* __restrict__ b_edge,
  const float* __restrict__ preW0, const float* __restrict__ pre_b0,
  const float* __restrict__ preW1, const float* __restrict__ pre_b1,
  const float* __restrict__ postW0, const float* __restrict__ post_b0,
  const float* __restrict__ postW1, const float* __restrict__ post_b1,
  const float* __restrict__ Wlin, const float* __restrict__ b_lin,
  const float* __restrict__ ln_g, const float* __restrict__ ln_b,
  const int* __restrict__ off, const int* __restrict__ eids,
  float* __restrict__ out)
{
  const int n = blockIdx.x;
  const int c = threadIdx.x;
  const int t = c >> 5, f = c & 31;
  __shared__ float xdS[128], xsS[128], eaS[32], hS[128];
  __shared__ float aggS[5][128], hpS[128], vS[128], red[4];

  const float xd = x[(size_t)n*128 + c];
  xdS[c] = xd;
  const int e0 = off[n], e1 = off[n+1];
  const int deg = e1 - e0;
  float sum = 0.f, sq = 0.f, mn = __builtin_inff(), mx = -__builtin_inff();
  __syncthreads();

  for (int idx = e0; idx < e1; ++idx){
    const int e = eids[idx];
    const int s = ei[e];
    xsS[c] = x[(size_t)s*128 + c];
    if (c < 32){
      float acc = b_edge[c];
      #pragma unroll
      for (int ii = 0; ii < 16; ++ii) acc = fmaf(eattr[(size_t)e*16 + ii], Wedge[ii*32 + c], acc);
      eaS[c] = acc;
    }
    __syncthreads();
    float acc = pre_b0[c];
    const float* W0 = preW0 + t*3072 + f;
    #pragma unroll 8
    for (int k = 0; k < 32; ++k) acc = fmaf(xdS[t*32+k], W0[k*32], acc);
    #pragma unroll 8
    for (int k = 0; k < 32; ++k) acc = fmaf(xsS[t*32+k], W0[(32+k)*32], acc);
    #pragma unroll 8
    for (int k = 0; k < 32; ++k) acc = fmaf(eaS[k], W0[(64+k)*32], acc);
    hS[c] = fmaxf(acc, 0.f);
    __syncthreads();
    float m = pre_b1[c];
    const float* W1 = preW1 + t*1024 + f;
    #pragma unroll 8
    for (int g = 0; g < 32; ++g) m = fmaf(hS[t*32+g], W1[g*32], m);
    sum += m; sq = fmaf(m, m, sq); mn = fminf(mn, m); mx = fmaxf(mx, m);
    __syncthreads();
  }
  const float d = (float)deg;
  const float denom = fmaxf(d, 1.f);
  const float mean = sum / denom;
  const float sd = sqrtf(fmaxf(sq/denom - mean*mean, 0.f) + 1e-5f);
  const float mnz = (deg > 0) ? mn : 0.f;
  const float mxz = (deg > 0) ? mx : 0.f;
  const float logd = logf(denom + 1.f);
  const float s1 = logd / ADL, s2 = ADL / logd;
  aggS[0][c] = sum; aggS[1][c] = mean; aggS[2][c] = mnz; aggS[3][c] = mxz; aggS[4][c] = sd;
  __syncthreads();
  float acc0 = post_b0[c];
  const float* P0 = postW0 + t*16384 + f;
  #pragma unroll 8
  for (int k = 0; k < 32; ++k) acc0 = fmaf(xdS[t*32+k], P0[k*32], acc0);
  float pa0 = 0.f, pa1 = 0.f, pa2 = 0.f;
  for (int a = 0; a < 5; ++a){
    const float* ag = &aggS[a][t*32];
    const float* Pb = P0 + (32 + a*32)*32;
    #pragma unroll 8
    for (int k = 0; k < 32; ++k){
      const float av = ag[k];
      pa0 = fmaf(av, Pb[k*32], pa0);
      pa1 = fmaf(av, Pb[(160+k)*32], pa1);
      pa2 = fmaf(av, Pb[(320+k)*32], pa2);
    }
  }
  hpS[c] = fmaxf(acc0 + pa0 + s1*pa1 + s2*pa2, 0.f);
  __syncthreads();
  float v = post_b1[c];
  const float* PW1 = postW1 + t*1024 + f;
  #pragma unroll 8
  for (int g = 0; g < 32; ++g) v = fmaf(hpS[t*32+g], PW1[g*32], v);
  vS[c] = v;
  __syncthreads();
  float l = b_lin[c];
  #pragma unroll 8
  for (int k = 0; k < 128; ++k) l = fmaf(vS[k], Wlin[k*128 + c], l);
  float ps = l, ps2 = l*l;
  #pragma unroll
  for (int o = 32; o >= 1; o >>= 1){ ps += __shfl_xor(ps, o); ps2 += __shfl_xor(ps2, o); }
  if ((c & 63) == 0){ red[c>>6] = ps; red[2 + (c>>6)] = ps2; }
  __syncthreads();
  const float mu = (red[0] + red[1]) * (1.f/128.f);
  const float var = fmaxf((red[2] + red[3]) * (1.f/128.f) - mu*mu, 0.f);
  const float rstd = rsqrtf(var + 1e-5f);
  out[(size_t)n*128 + c] = xd + fmaxf((l - mu)*rstd*ln_g[c] + ln_b[c], 0.f);
}

// ======================= launch =======================
extern "C" void kernel_launch(void* const* d_in, const int* in_sizes, int n_in,
                              void* d_out, int out_size, void* d_ws, size_t ws_size,
                              hipStream_t stream){
  const float* x       = (const float*)d_in[0];
  const int*   ei      = (const int*)d_in[1];
  const float* eattr   = (const float*)d_in[2];
  const float* Wedge   = (const float*)d_in[3];
  const float* b_edge  = (const float*)d_in[4];
  const float* preW0   = (const float*)d_in[5];
  const float* pre_b0  = (const float*)d_in[6];
  const float* preW1   = (const float*)d_in[7];
  const float* pre_b1  = (const float*)d_in[8];
  const float* postW0  = (const float*)d_in[9];
  const float* post_b0 = (const float*)d_in[10];
  const float* postW1  = (const float*)d_in[11];
  const float* post_b1 = (const float*)d_in[12];
  const float* Wlin    = (const float*)d_in[13];
  const float* b_lin   = (const float*)d_in[14];
  const float* ln_g    = (const float*)d_in[15];
  const float* ln_b    = (const float*)d_in[16];

  char* ws = (char*)d_ws;
  size_t o = 0;
  auto alloc = [&](size_t bytes)->char*{
    char* p = ws + o; o = (o + bytes + 255) & ~((size_t)255); return p;
  };
  int* off    = (int*)alloc((NN + 1) * 4);
  int* cnt    = (int*)alloc(NN * 4);
  int* cursor = (int*)alloc(NN * 4);
  int* eids   = (int*)alloc(NE * 4);
  float* preW0T  = (float*)alloc(12288 * 4);
  float* preW1T  = (float*)alloc(4096 * 4);
  float* postW0T = (float*)alloc(65536 * 4);
  float* postW1T = (float*)alloc(4096 * 4);
  float* WlinT   = (float*)alloc(16384 * 4);
  float* eaC     = (float*)alloc((size_t)NE * 32 * 4);
  float* agg     = (float*)alloc((size_t)NN * 512 * 4);
  const size_t need = o;

  // CSR build (both paths)
  k_zero<<<(NN + 255)/256, 256, 0, stream>>>(cnt, cursor);
  k_hist<<<(NE + 255)/256, 256, 0, stream>>>(ei, cnt);
  k_scan<<<1, 1024, 0, stream>>>(cnt, off);
  k_scatter<<<(NE + 255)/256, 256, 0, stream>>>(ei, off, cursor, eids);

  if (ws_size < need){
    k_mono<<<NN, 128, 0, stream>>>(x, ei, eattr, Wedge, b_edge,
                                   preW0, pre_b0, preW1, pre_b1,
                                   postW0, post_b0, postW1, post_b1,
                                   Wlin, b_lin, ln_g, ln_b,
                                   off, eids, (float*)d_out);
    return;
  }

  k_prep<<<256, 256, 0, stream>>>(preW0, preW1, postW0, postW1, Wlin,
                                  preW0T, preW1T, postW0T, postW1T, WlinT);
  k_ea<<<(NE + 7)/8, 256, 0, stream>>>(eattr, Wedge, b_edge, eids, eaC);
  k_edge2<<<NN/8, 256, 0, stream>>>(x, ei, eaC, preW0T, preW1,
                                    pre_b0, pre_b1, off, eids, agg);
  k_post<<<NN/12, 128, 0, stream>>>(x, agg, off, postW0T, postW1T, WlinT,
                                    post_b0, post_b1, b_lin, ln_g, ln_b,
                                    (float*)d_out);
}

// Round 7
// 1029.809 us; speedup vs baseline: 2.7747x; 2.7747x over previous
//
#include <hip/hip_runtime.h>
#include <hip/hip_bf16.h>

#define NN 30000
#define NE 480000
#define ADL 2.8332133440562162f   // ln(17)

typedef unsigned int u32;

// ======================= CSR build =======================
__global__ void k_zero(int* __restrict__ cnt, int* __restrict__ cursor){
  int i = blockIdx.x * blockDim.x + threadIdx.x;
  if (i < NN){ cnt[i] = 0; cursor[i] = 0; }
}

__global__ void k_hist(const int* __restrict__ ei, int* __restrict__ cnt){
  int e = blockIdx.x * blockDim.x + threadIdx.x;
  if (e < NE) atomicAdd(&cnt[ei[NE + e]], 1);
}

__global__ __launch_bounds__(1024) void k_scan(const int* __restrict__ cnt, int* __restrict__ off){
  __shared__ int buf[1024];
  __shared__ int s_carry;
  const int tid = threadIdx.x;
  if (tid == 0) s_carry = 0;
  __syncthreads();
  for (int base = 0; base < NN; base += 1024){
    int i = base + tid;
    int v = (i < NN) ? cnt[i] : 0;
    buf[tid] = v;
    __syncthreads();
    for (int s = 1; s < 1024; s <<= 1){
      int t = (tid >= s) ? buf[tid - s] : 0;
      __syncthreads();
      buf[tid] += t;
      __syncthreads();
    }
    int carry = s_carry;
    if (i < NN) off[i] = carry + buf[tid] - v;
    __syncthreads();
    if (tid == 0) s_carry = carry + buf[1023];
    __syncthreads();
  }
  if (tid == 0) off[NN] = s_carry;
}

__global__ void k_scatter(const int* __restrict__ ei, const int* __restrict__ off,
                          int* __restrict__ cursor, int* __restrict__ eids){
  int e = blockIdx.x * blockDim.x + threadIdx.x;
  if (e < NE){
    int d = ei[NE + e];
    int pos = off[d] + atomicAdd(&cursor[d], 1);
    eids[pos] = e;
  }
}

// ======================= weight transposes (f32 -> f32, [c][k]) =======================
__global__ void k_prep(const float* __restrict__ preW0, const float* __restrict__ preW1,
                       const float* __restrict__ postW0, const float* __restrict__ postW1,
                       const float* __restrict__ Wlin,
                       float* __restrict__ preW0T, float* __restrict__ preW1T,
                       float* __restrict__ postW0T, float* __restrict__ postW1T,
                       float* __restrict__ WlinT)
{
  int i = blockIdx.x * blockDim.x + threadIdx.x;
  if (i < 65536){ int c = i >> 9, kk = i & 511;
    postW0T[i] = postW0[(c >> 5)*16384 + kk*32 + (c & 31)]; }
  if (i < 12288){ int c = i / 96, k = i % 96;
    preW0T[i] = preW0[(c >> 5)*3072 + k*32 + (c & 31)]; }
  if (i < 4096){ int c = i >> 5, g = i & 31;
    preW1T[i]  = preW1[(c >> 5)*1024 + g*32 + (c & 31)];
    postW1T[i] = postW1[(c >> 5)*1024 + g*32 + (c & 31)]; }
  if (i < 16384){ int c = i >> 7, k = i & 127; WlinT[i] = Wlin[k*128 + c]; }
}

// ======================= ea precompute, CSR-ordered =======================
__global__ __launch_bounds__(256) void k_ea(const float* __restrict__ eattr,
                                            const float* __restrict__ Wedge,
                                            const float* __restrict__ b_edge,
                                            const int* __restrict__ eids,
                                            float* __restrict__ eaC)
{
  __shared__ float WS[512];
  __shared__ float bS[32];
  const int tid = threadIdx.x;
  WS[tid]       = Wedge[tid];
  WS[tid + 256] = Wedge[tid + 256];
  if (tid < 32) bS[tid] = b_edge[tid];
  __syncthreads();
  const int g = tid & 31;
  const int pos = blockIdx.x * 8 + (tid >> 5);
  if (pos < NE){
    const int e = eids[pos];
    const float* ar = eattr + (size_t)e * 16;
    float acc = bS[g];
    #pragma unroll
    for (int ii = 0; ii < 16; ++ii) acc = fmaf(ar[ii], WS[ii*32 + g], acc);
    eaC[(size_t)pos*32 + g] = acc;
  }
}

// ======================= edge phase v2b: lane=edge, wave=tower, SGPR weights =======================
// R6 fix: __launch_bounds__(256,2) so A[24] float4 stays in VGPRs (R6's (256,4) spilled to
// scratch: VGPR_Count=64, FETCH 5.8GB, VALUBusy 6%). Layer0 uses 4 partial accumulators for ILP.
__global__ __launch_bounds__(256, 2) void k_edge2(
  const float* __restrict__ x, const int* __restrict__ ei,
  const float* __restrict__ eaC,
  const float* __restrict__ preW0T, const float* __restrict__ preW1,
  const float* __restrict__ pre_b0, const float* __restrict__ pre_b1,
  const int* __restrict__ off, const int* __restrict__ eids,
  float* __restrict__ agg)
{
  const int tid  = threadIdx.x;
  const int lane = tid & 63;
  const int t    = __builtin_amdgcn_readfirstlane(tid >> 6);   // tower, provably wave-uniform
  const int n0   = blockIdx.x * 8;

  __shared__ float hm[64][133];
  __shared__ int offS[9];
  __shared__ int sidS[64];

  if (tid < 9) offS[tid] = off[n0 + tid];
  __syncthreads();
  const int e0 = offS[0], e1 = offS[8];

  // scan state (threads 0..127 only)
  float s_sum = 0.f, s_sq = 0.f;
  float s_mn = __builtin_inff(), s_mx = -__builtin_inff();
  int cur = 0;

  for (int base = e0; base < e1; base += 64){
    const int nv = min(64, e1 - base);
    if (tid < nv) sidS[tid] = ei[eids[base + tid]];
    __syncthreads();

    // ---------- compute phase: one edge per lane ----------
    {
      const int jl  = (lane < nv) ? lane : 0;
      const int pos = base + jl;
      // dst node: branchless rank within the block's 8-node offset table
      int d = 0;
      #pragma unroll
      for (int q = 0; q < 8; ++q) d += (pos >= offS[q+1]) ? 1 : 0;
      const int dn = n0 + d;
      const int sn = sidS[jl];

      float4 A[24];
      const float* xdp = x + (size_t)dn*128 + t*32;
      const float* xsp = x + (size_t)sn*128 + t*32;
      const float* eap = eaC + (size_t)pos*32;
      #pragma unroll
      for (int q = 0; q < 8; ++q) A[q]      = *(const float4*)(xdp + q*4);
      #pragma unroll
      for (int q = 0; q < 8; ++q) A[8 + q]  = *(const float4*)(xsp + q*4);
      #pragma unroll
      for (int q = 0; q < 8; ++q) A[16 + q] = *(const float4*)(eap + q*4);

      // layer0: g rolled (wave-uniform weight rows -> s_load), 4-way acc ILP, h -> LDS
      for (int g = 0; g < 32; ++g){
        const float* Wg = preW0T + (size_t)(t*32 + g)*96;
        float a0 = pre_b0[t*32 + g], a1 = 0.f, a2 = 0.f, a3 = 0.f;
        #pragma unroll
        for (int q = 0; q < 6; ++q){
          const float4 A0 = A[q*4+0], A1 = A[q*4+1], A2 = A[q*4+2], A3 = A[q*4+3];
          a0 = fmaf(A0.x, Wg[q*16+ 0], a0); a0 = fmaf(A0.y, Wg[q*16+ 1], a0);
          a0 = fmaf(A0.z, Wg[q*16+ 2], a0); a0 = fmaf(A0.w, Wg[q*16+ 3], a0);
          a1 = fmaf(A1.x, Wg[q*16+ 4], a1); a1 = fmaf(A1.y, Wg[q*16+ 5], a1);
          a1 = fmaf(A1.z, Wg[q*16+ 6], a1); a1 = fmaf(A1.w, Wg[q*16+ 7], a1);
          a2 = fmaf(A2.x, Wg[q*16+ 8], a2); a2 = fmaf(A2.y, Wg[q*16+ 9], a2);
          a2 = fmaf(A2.z, Wg[q*16+10], a2); a2 = fmaf(A2.w, Wg[q*16+11], a2);
          a3 = fmaf(A3.x, Wg[q*16+12], a3); a3 = fmaf(A3.y, Wg[q*16+13], a3);
          a3 = fmaf(A3.z, Wg[q*16+14], a3); a3 = fmaf(A3.w, Wg[q*16+15], a3);
        }
        hm[lane][t*32 + g] = fmaxf((a0 + a1) + (a2 + a3), 0.f);
      }

      // layer1: m[f] accumulated in regs (f static via unroll), then overwrite hm with m
      float m[32];
      #pragma unroll
      for (int f = 0; f < 32; ++f) m[f] = pre_b1[t*32 + f];
      for (int g = 0; g < 32; ++g){
        const float hg = hm[lane][t*32 + g];
        const float* W1g = preW1 + t*1024 + g*32;   // original [t][g][f] layout: f contiguous
        #pragma unroll
        for (int f = 0; f < 32; ++f) m[f] = fmaf(hg, W1g[f], m[f]);
      }
      #pragma unroll
      for (int f = 0; f < 32; ++f) hm[lane][t*32 + f] = m[f];
    }
    __syncthreads();

    // ---------- scan phase: thread = channel, serial over window edges ----------
    if (tid < 128){
      for (int j = 0; j < nv; ++j){
        const int gpos = base + j;
        while (gpos >= offS[cur + 1]){
          const int deg = offS[cur + 1] - offS[cur];
          const size_t b = (size_t)(n0 + cur) * 512;
          agg[b + tid]       = s_sum;
          agg[b + 128 + tid] = s_sq;
          agg[b + 256 + tid] = (deg > 0) ? s_mn : 0.f;
          agg[b + 384 + tid] = (deg > 0) ? s_mx : 0.f;
          s_sum = 0.f; s_sq = 0.f;
          s_mn = __builtin_inff(); s_mx = -__builtin_inff();
          ++cur;
        }
        const float mv = hm[j][tid];
        s_sum += mv; s_sq = fmaf(mv, mv, s_sq);
        s_mn = fminf(s_mn, mv); s_mx = fmaxf(s_mx, mv);
      }
    }
    __syncthreads();
  }

  // final flush: remaining nodes (including degree-0)
  if (tid < 128){
    while (cur < 8){
      const int deg = offS[cur + 1] - offS[cur];
      const size_t b = (size_t)(n0 + cur) * 512;
      agg[b + tid]       = s_sum;
      agg[b + 128 + tid] = s_sq;
      agg[b + 256 + tid] = (deg > 0) ? s_mn : 0.f;
      agg[b + 384 + tid] = (deg > 0) ? s_mx : 0.f;
      s_sum = 0.f; s_sq = 0.f;
      s_mn = __builtin_inff(); s_mx = -__builtin_inff();
      ++cur;
    }
  }
}

// ======================= node phase: G=12 nodes/block, register-tiled =======================
__global__ __launch_bounds__(128, 2) void k_post(
  const float* __restrict__ x, const float* __restrict__ agg,
  const int* __restrict__ off,
  const float* __restrict__ postW0T, const float* __restrict__ postW1T,
  const float* __restrict__ WlinT,
  const float* __restrict__ post_b0, const float* __restrict__ post_b1,
  const float* __restrict__ b_lin, const float* __restrict__ ln_g,
  const float* __restrict__ ln_b,
  float* __restrict__ out)
{
  const int c = threadIdx.x;
  const int t = c >> 5;
  const int n0 = blockIdx.x * 12;

  __shared__ __align__(16) float aS[12][768];   // [xd | sum | mean | mn | mx | std] x 128
  __shared__ __align__(16) float hpS[12][128];
  __shared__ __align__(16) float vS[12][128];
  __shared__ float s1S[12], s2S[12], muS[12], rsS[12];

  #pragma unroll
  for (int n = 0; n < 12; ++n){
    const size_t nb = (size_t)(n0 + n);
    aS[n][c] = x[nb*128 + c];
    float sum = agg[nb*512 + c];
    float sq  = agg[nb*512 + 128 + c];
    float mnv = agg[nb*512 + 256 + c];
    float mxv = agg[nb*512 + 384 + c];
    int deg = off[n0+n+1] - off[n0+n];
    float denom = fmaxf((float)deg, 1.f);
    float mean = sum / denom;
    float sd = sqrtf(fmaxf(sq/denom - mean*mean, 0.f) + 1e-5f);
    aS[n][128 + c] = sum;  aS[n][256 + c] = mean;
    aS[n][384 + c] = mnv;  aS[n][512 + c] = mxv;  aS[n][640 + c] = sd;
  }
  if (c < 12){
    int deg = off[n0+c+1] - off[n0+c];
    float logd = logf(fmaxf((float)deg, 1.f) + 1.f);
    s1S[c] = logd / ADL; s2S[c] = ADL / logd;
  }
  __syncthreads();

  float acc[12], pa1[12], pa2[12];
  const float pb0 = post_b0[c];
  #pragma unroll
  for (int n = 0; n < 12; ++n){ acc[n] = pb0; pa1[n] = 0.f; pa2[n] = 0.f; }
  const float* Wp = postW0T + (size_t)c * 512;
  #pragma unroll
  for (int k4 = 0; k4 < 8; ++k4){
    float4 w = *(const float4*)(Wp + k4*4);
    #pragma unroll
    for (int n = 0; n < 12; ++n){
      float4 a = *(const float4*)&aS[n][t*32 + k4*4];
      acc[n] = fmaf(a.x, w.x, acc[n]); acc[n] = fmaf(a.y, w.y, acc[n]);
      acc[n] = fmaf(a.z, w.z, acc[n]); acc[n] = fmaf(a.w, w.w, acc[n]);
    }
  }
  for (int a = 0; a < 5; ++a){
    #pragma unroll
    for (int k4 = 0; k4 < 8; ++k4){
      float4 w0v = *(const float4*)(Wp + 32  + a*32 + k4*4);
      float4 w1v = *(const float4*)(Wp + 192 + a*32 + k4*4);
      float4 w2v = *(const float4*)(Wp + 352 + a*32 + k4*4);
      #pragma unroll
      for (int n = 0; n < 12; ++n){
        float4 av = *(const float4*)&aS[n][128 + a*128 + t*32 + k4*4];
        acc[n] = fmaf(av.x, w0v.x, acc[n]); acc[n] = fmaf(av.y, w0v.y, acc[n]);
        acc[n] = fmaf(av.z, w0v.z, acc[n]); acc[n] = fmaf(av.w, w0v.w, acc[n]);
        pa1[n] = fmaf(av.x, w1v.x, pa1[n]); pa1[n] = fmaf(av.y, w1v.y, pa1[n]);
        pa1[n] = fmaf(av.z, w1v.z, pa1[n]); pa1[n] = fmaf(av.w, w1v.w, pa1[n]);
        pa2[n] = fmaf(av.x, w2v.x, pa2[n]); pa2[n] = fmaf(av.y, w2v.y, pa2[n]);
        pa2[n] = fmaf(av.z, w2v.z, pa2[n]); pa2[n] = fmaf(av.w, w2v.w, pa2[n]);
      }
    }
  }
  #pragma unroll
  for (int n = 0; n < 12; ++n)
    hpS[n][c] = fmaxf(acc[n] + s1S[n]*pa1[n] + s2S[n]*pa2[n], 0.f);
  __syncthreads();

  float w1r[32];
  #pragma unroll
  for (int q = 0; q < 8; ++q) *(float4*)&w1r[q*4] = *(const float4*)(postW1T + (size_t)c*32 + q*4);
  float a2[12];
  const float pb1v = post_b1[c];
  #pragma unroll
  for (int n = 0; n < 12; ++n) a2[n] = pb1v;
  #pragma unroll
  for (int g4 = 0; g4 < 8; ++g4){
    #pragma unroll
    for (int n = 0; n < 12; ++n){
      float4 h = *(const float4*)&hpS[n][t*32 + g4*4];
      a2[n] = fmaf(h.x, w1r[g4*4+0], a2[n]); a2[n] = fmaf(h.y, w1r[g4*4+1], a2[n]);
      a2[n] = fmaf(h.z, w1r[g4*4+2], a2[n]); a2[n] = fmaf(h.w, w1r[g4*4+3], a2[n]);
    }
  }
  #pragma unroll
  for (int n = 0; n < 12; ++n) vS[n][c] = a2[n];
  __syncthreads();

  float a3[12];
  const float blv = b_lin[c];
  #pragma unroll
  for (int n = 0; n < 12; ++n) a3[n] = blv;
  const float* Wl = WlinT + (size_t)c * 128;
  #pragma unroll 8
  for (int k4 = 0; k4 < 32; ++k4){
    float4 w = *(const float4*)(Wl + k4*4);
    #pragma unroll
    for (int n = 0; n < 12; ++n){
      float4 v = *(const float4*)&vS[n][k4*4];
      a3[n] = fmaf(v.x, w.x, a3[n]); a3[n] = fmaf(v.y, w.y, a3[n]);
      a3[n] = fmaf(v.z, w.z, a3[n]); a3[n] = fmaf(v.w, w.w, a3[n]);
    }
  }

  #pragma unroll
  for (int n = 0; n < 12; ++n) hpS[n][c] = a3[n];
  __syncthreads();
  {
    const int n = c >> 3, seg = c & 7;
    if (n < 12){
      float ps = 0.f, ps2 = 0.f;
      #pragma unroll
      for (int k = 0; k < 16; ++k){
        float v = hpS[n][seg*16 + k];
        ps += v; ps2 = fmaf(v, v, ps2);
      }
      ps += __shfl_xor(ps, 1); ps2 += __shfl_xor(ps2, 1);
      ps += __shfl_xor(ps, 2); ps2 += __shfl_xor(ps2, 2);
      ps += __shfl_xor(ps, 4); ps2 += __shfl_xor(ps2, 4);
      if (seg == 0){
        float mu = ps * (1.f/128.f);
        float var = fmaxf(ps2 * (1.f/128.f) - mu*mu, 0.f);
        muS[n] = mu; rsS[n] = rsqrtf(var + 1e-5f);
      }
    }
  }
  __syncthreads();
  const float gv = ln_g[c], bv = ln_b[c];
  #pragma unroll
  for (int n = 0; n < 12; ++n){
    float o = aS[n][c] + fmaxf((a3[n] - muS[n])*rsS[n]*gv + bv, 0.f);
    out[(size_t)(n0 + n)*128 + c] = o;
  }
}

// ======================= fallback: proven monolithic kernel (R3, f32) =======================
__global__ __launch_bounds__(128) void k_mono(
  const float* __restrict__ x, const int* __restrict__ ei,
  const float* __restrict__ eattr,
  const float* __restrict__ Wedge, const float* __restrict__ b_edge,
  const float* __restrict__ preW0, const float* __restrict__ pre_b0,
  const float* __restrict__ preW1, const float* __restrict__ pre_b1,
  const float* __restrict__ postW0, const float* __restrict__ post_b0,
  const float* __restrict__ postW1, const float* __restrict__ post_b1,
  const float* __restrict__ Wlin, const float* __restrict__ b_lin,
  const float* __restrict__ ln_g, const float* __restrict__ ln_b,
  const int* __restrict__ off, const int* __restrict__ eids,
  float* __restrict__ out)
{
  const int n = blockIdx.x;
  const int c = threadIdx.x;
  const int t = c >> 5, f = c & 31;
  __shared__ float xdS[128], xsS[128], eaS[32], hS[128];
  __shared__ float aggS[5][128], hpS[128], vS[128], red[4];

  const float xd = x[(size_t)n*128 + c];
  xdS[c] = xd;
  const int e0 = off[n], e1 = off[n+1];
  const int deg = e1 - e0;
  float sum = 0.f, sq = 0.f, mn = __builtin_inff(), mx = -__builtin_inff();
  __syncthreads();

  for (int idx = e0; idx < e1; ++idx){
    const int e = eids[idx];
    const int s = ei[e];
    xsS[c] = x[(size_t)s*128 + c];
    if (c < 32){
      float acc = b_edge[c];
      #pragma unroll
      for (int ii = 0; ii < 16; ++ii) acc = fmaf(eattr[(size_t)e*16 + ii], Wedge[ii*32 + c], acc);
      eaS[c] = acc;
    }
    __syncthreads();
    float acc = pre_b0[c];
    const float* W0 = preW0 + t*3072 + f;
    #pragma unroll 8
    for (int k = 0; k < 32; ++k) acc = fmaf(xdS[t*32+k], W0[k*32], acc);
    #pragma unroll 8
    for (int k = 0; k < 32; ++k) acc = fmaf(xsS[t*32+k], W0[(32+k)*32], acc);
    #pragma unroll 8
    for (int k = 0; k < 32; ++k) acc = fmaf(eaS[k], W0[(64+k)*32], acc);
    hS[c] = fmaxf(acc, 0.f);
    __syncthreads();
    float m = pre_b1[c];
    const float* W1 = preW1 + t*1024 + f;
    #pragma unroll 8
    for (int g = 0; g < 32; ++g) m = fmaf(hS[t*32+g], W1[g*32], m);
    sum += m; sq = fmaf(m, m, sq); mn = fminf(mn, m); mx = fmaxf(mx, m);
    __syncthreads();
  }
  const float d = (float)deg;
  const float denom = fmaxf(d, 1.f);
  const float mean = sum / denom;
  const float sd = sqrtf(fmaxf(sq/denom - mean*mean, 0.f) + 1e-5f);
  const float mnz = (deg > 0) ? mn : 0.f;
  const float mxz = (deg > 0) ? mx : 0.f;
  const float logd = logf(denom + 1.f);
  const float s1 = logd / ADL, s2 = ADL / logd;
  aggS[0][c] = sum; aggS[1][c] = mean; aggS[2][c] = mnz; aggS[3][c] = mxz; aggS[4][c] = sd;
  __syncthreads();
  float acc0 = post_b0[c];
  const float* P0 = postW0 + t*16384 + f;
  #pragma unroll 8
  for (int k = 0; k < 32; ++k) acc0 = fmaf(xdS[t*32+k], P0[k*32], acc0);
  float pa0 = 0.f, pa1 = 0.f, pa2 = 0.f;
  for (int a = 0; a < 5; ++a){
    const float* ag = &aggS[a][t*32];
    const float* Pb = P0 + (32 + a*32)*32;
    #pragma unroll 8
    for (int k = 0; k < 32; ++k){
      const float av = ag[k];
      pa0 = fmaf(av, Pb[k*32], pa0);
      pa1 = fmaf(av, Pb[(160+k)*32], pa1);
      pa2 = fmaf(av, Pb[(320+k)*32], pa2);
    }
  }
  hpS[c] = fmaxf(acc0 + pa0 + s1*pa1 + s2*pa2, 0.f);
  __syncthreads();
  float v = post_b1[c];
  const float* PW1 = postW1 + t*1024 + f;
  #pragma unroll 8
  for (int g = 0; g < 32; ++g) v = fmaf(hpS[t*32+g], PW1[g*32], v);
  vS[c] = v;
  __syncthreads();
  float l = b_lin[c];
  #pragma unroll 8
  for (int k = 0; k < 128; ++k) l = fmaf(vS[k], Wlin[k*128 + c], l);
  float ps = l, ps2 = l*l;
  #pragma unroll
  for (int o = 32; o >= 1; o >>= 1){ ps += __shfl_xor(ps, o); ps2 += __shfl_xor(ps2, o); }
  if ((c & 63) == 0){ red[c>>6] = ps; red[2 + (c>>6)] = ps2; }
  __syncthreads();
  const float mu = (red[0] + red[1]) * (1.f/128.f);
  const float var = fmaxf((red[2] + red[3]) * (1.f/128.f) - mu*mu, 0.f);
  const float rstd = rsqrtf(var + 1e-5f);
  out[(size_t)n*128 + c] = xd + fmaxf((l - mu)*rstd*ln_g[c] + ln_b[c], 0.f);
}

// ======================= launch =======================
extern "C" void kernel_launch(void* const* d_in, const int* in_sizes, int n_in,
                              void* d_out, int out_size, void* d_ws, size_t ws_size,
                              hipStream_t stream){
  const float* x       = (const float*)d_in[0];
  const int*   ei      = (const int*)d_in[1];
  const float* eattr   = (const float*)d_in[2];
  const float* Wedge   = (const float*)d_in[3];
  const float* b_edge  = (const float*)d_in[4];
  const float* preW0   = (const float*)d_in[5];
  const float* pre_b0  = (const float*)d_in[6];
  const float* preW1   = (const float*)d_in[7];
  const float* pre_b1  = (const float*)d_in[8];
  const float* postW0  = (const float*)d_in[9];
  const float* post_b0 = (const float*)d_in[10];
  const float* postW1  = (const float*)d_in[11];
  const float* post_b1 = (const float*)d_in[12];
  const float* Wlin    = (const float*)d_in[13];
  const float* b_lin   = (const float*)d_in[14];
  const float* ln_g    = (const float*)d_in[15];
  const float* ln_b    = (const float*)d_in[16];

  char* ws = (char*)d_ws;
  size_t o = 0;
  auto alloc = [&](size_t bytes)->char*{
    char* p = ws + o; o = (o + bytes + 255) & ~((size_t)255); return p;
  };
  int* off    = (int*)alloc((NN + 1) * 4);
  int* cnt    = (int*)alloc(NN * 4);
  int* cursor = (int*)alloc(NN * 4);
  int* eids   = (int*)alloc(NE * 4);
  float* preW0T  = (float*)alloc(12288 * 4);
  float* preW1T  = (float*)alloc(4096 * 4);
  float* postW0T = (float*)alloc(65536 * 4);
  float* postW1T = (float*)alloc(4096 * 4);
  float* WlinT   = (float*)alloc(16384 * 4);
  float* eaC     = (float*)alloc((size_t)NE * 32 * 4);
  float* agg     = (float*)alloc((size_t)NN * 512 * 4);
  const size_t need = o;

  // CSR build (both paths)
  k_zero<<<(NN + 255)/256, 256, 0, stream>>>(cnt, cursor);
  k_hist<<<(NE + 255)/256, 256, 0, stream>>>(ei, cnt);
  k_scan<<<1, 1024, 0, stream>>>(cnt, off);
  k_scatter<<<(NE + 255)/256, 256, 0, stream>>>(ei, off, cursor, eids);

  if (ws_size < need){
    k_mono<<<NN, 128, 0, stream>>>(x, ei, eattr, Wedge, b_edge,
                                   preW0, pre_b0, preW1, pre_b1,
                                   postW0, post_b0, postW1, post_b1,
                                   Wlin, b_lin, ln_g, ln_b,
                                   off, eids, (float*)d_out);
    return;
  }

  k_prep<<<256, 256, 0, stream>>>(preW0, preW1, postW0, postW1, Wlin,
                                  preW0T, preW1T, postW0T, postW1T, WlinT);
  k_ea<<<(NE + 7)/8, 256, 0, stream>>>(eattr, Wedge, b_edge, eids, eaC);
  k_edge2<<<NN/8, 256, 0, stream>>>(x, ei, eaC, preW0T, preW1,
                                    pre_b0, pre_b1, off, eids, agg);
  k_post<<<NN/12, 128, 0, stream>>>(x, agg, off, postW0T, postW1T, WlinT,
                                    post_b0, post_b1, b_lin, ln_g, ln_b,
                                    (float*)d_out);
}

// Round 8
// 653.165 us; speedup vs baseline: 4.3747x; 1.5766x over previous
//
#include <hip/hip_runtime.h>
#include <hip/hip_bf16.h>

#define NN 30000
#define NE 480000
#define ADL 2.8332133440562162f   // ln(17)

typedef unsigned int u32;
typedef unsigned short u16;

typedef _Float16 half2v __attribute__((ext_vector_type(2)));

__device__ __forceinline__ u16 f2h(float f){
  union { _Float16 h; u16 u; } v; v.h = (_Float16)f; return v.u;
}
__device__ __forceinline__ u32 pack2(float lo, float hi){
  return (u32)f2h(lo) | ((u32)f2h(hi) << 16);
}
__device__ __forceinline__ float dot2f(u32 a, u32 b, float c){
#if defined(__has_builtin) && __has_builtin(__builtin_amdgcn_fdot2)
  union U { u32 u; half2v h; };
  U ua, ub; ua.u = a; ub.u = b;
  return __builtin_amdgcn_fdot2(ua.h, ub.h, c, false);
#else
  float r;
  asm("v_dot2_f32_f16 %0, %1, %2, %3" : "=v"(r) : "v"(a), "v"(b), "v"(c));
  return r;
#endif
}

// ======================= CSR build =======================
__global__ void k_zero(int* __restrict__ cnt, int* __restrict__ cursor){
  int i = blockIdx.x * blockDim.x + threadIdx.x;
  if (i < NN){ cnt[i] = 0; cursor[i] = 0; }
}

__global__ void k_hist(const int* __restrict__ ei, int* __restrict__ cnt){
  int e = blockIdx.x * blockDim.x + threadIdx.x;
  if (e < NE) atomicAdd(&cnt[ei[NE + e]], 1);
}

__global__ __launch_bounds__(1024) void k_scan(const int* __restrict__ cnt, int* __restrict__ off){
  __shared__ int buf[1024];
  __shared__ int s_carry;
  const int tid = threadIdx.x;
  if (tid == 0) s_carry = 0;
  __syncthreads();
  for (int base = 0; base < NN; base += 1024){
    int i = base + tid;
    int v = (i < NN) ? cnt[i] : 0;
    buf[tid] = v;
    __syncthreads();
    for (int s = 1; s < 1024; s <<= 1){
      int t = (tid >= s) ? buf[tid - s] : 0;
      __syncthreads();
      buf[tid] += t;
      __syncthreads();
    }
    int carry = s_carry;
    if (i < NN) off[i] = carry + buf[tid] - v;
    __syncthreads();
    if (tid == 0) s_carry = carry + buf[1023];
    __syncthreads();
  }
  if (tid == 0) off[NN] = s_carry;
}

__global__ void k_scatter(const int* __restrict__ ei, const int* __restrict__ off,
                          int* __restrict__ cursor, int* __restrict__ eids){
  int e = blockIdx.x * blockDim.x + threadIdx.x;
  if (e < NE){
    int d = ei[NE + e];
    int pos = off[d] + atomicAdd(&cursor[d], 1);
    eids[pos] = e;
  }
}

// ======================= weight prep =======================
// f32 transposes for k_post + f16-packed per-channel weights for k_edge3.
__global__ void k_prep(const float* __restrict__ preW0, const float* __restrict__ preW1,
                       const float* __restrict__ postW0, const float* __restrict__ postW1,
                       const float* __restrict__ Wlin,
                       u32* __restrict__ preW0H, u32* __restrict__ preW1H,
                       float* __restrict__ postW0T, float* __restrict__ postW1T,
                       float* __restrict__ WlinT)
{
  int i = blockIdx.x * blockDim.x + threadIdx.x;
  if (i < 65536){ int c = i >> 9, kk = i & 511;
    postW0T[i] = postW0[(c >> 5)*16384 + kk*32 + (c & 31)]; }
  if (i < 6144){          // preW0H[c][q]: pair (k=2q, k=2q+1) of preW0[t][k][f]
    int c = i / 48, q = i % 48;
    int t = c >> 5, f = c & 31;
    preW0H[i] = pack2(preW0[t*3072 + (2*q)*32 + f], preW0[t*3072 + (2*q+1)*32 + f]);
  }
  if (i < 2048){          // preW1H[c][q]: pair (g=2q, g=2q+1) of preW1[t][g][f]
    int c = i / 16, q = i % 16;
    int t = c >> 5, f = c & 31;
    preW1H[i] = pack2(preW1[t*1024 + (2*q)*32 + f], preW1[t*1024 + (2*q+1)*32 + f]);
  }
  if (i < 4096){ int c = i >> 5, g = i & 31;
    postW1T[i] = postW1[(c >> 5)*1024 + g*32 + (c & 31)]; }
  if (i < 16384){ int c = i >> 7, k = i & 127; WlinT[i] = Wlin[k*128 + c]; }
}

// ======================= ea precompute, CSR-ordered, f16 output =======================
__global__ __launch_bounds__(256) void k_ea(const float* __restrict__ eattr,
                                            const float* __restrict__ Wedge,
                                            const float* __restrict__ b_edge,
                                            const int* __restrict__ eids,
                                            u16* __restrict__ eaH)
{
  __shared__ float WS[512];
  __shared__ float bS[32];
  const int tid = threadIdx.x;
  WS[tid]       = Wedge[tid];
  WS[tid + 256] = Wedge[tid + 256];
  if (tid < 32) bS[tid] = b_edge[tid];
  __syncthreads();
  const int g = tid & 31;
  const int pos = blockIdx.x * 8 + (tid >> 5);
  if (pos < NE){
    const int e = eids[pos];
    const float* ar = eattr + (size_t)e * 16;
    float acc = bS[g];
    #pragma unroll
    for (int ii = 0; ii < 16; ++ii) acc = fmaf(ar[ii], WS[ii*32 + g], acc);
    eaH[(size_t)pos*32 + g] = f2h(acc);
  }
}

// ======================= edge phase v3: f16 dot2, lane=channel, VGPR weights =======================
// R5 structure (proven 503us @ 46% VALU) with f16 pairs: halves both instruction count and
// LDS operand bytes. Weights: 64 u32 per lane (vs 128 f32 in R5 -> compiler kept ~88 and
// re-loaded; halved footprint should stay resident).
__global__ __launch_bounds__(128, 2) void k_edge3(
  const float* __restrict__ x, const int* __restrict__ ei,
  const u32* __restrict__ eaHu,
  const u32* __restrict__ preW0H, const u32* __restrict__ preW1H,
  const float* __restrict__ pre_b0, const float* __restrict__ pre_b1,
  const int* __restrict__ off, const int* __restrict__ eids,
  float* __restrict__ agg)
{
  const int c = threadIdx.x;        // channel 0..127
  const int t = c >> 5;             // tower

  __shared__ u32 xdH[64];           // dst-x packed pairs (128 ch -> 64 u32)
  __shared__ u32 xsH[64];           // src-x packed pairs
  __shared__ u32 eaS[16];           // ea packed pairs (32 ch -> 16 u32)
  __shared__ u32 hP[64];            // hidden packed pairs (written as u16 halves)
  __shared__ int sidS[64];

  // per-lane packed weights in VGPRs (statically indexed)
  u32 w0p[48], w1p[16];
  #pragma unroll
  for (int q = 0; q < 12; ++q) *(uint4*)&w0p[q*4] = *(const uint4*)(preW0H + (size_t)c*48 + q*4);
  #pragma unroll
  for (int q = 0; q < 4; ++q)  *(uint4*)&w1p[q*4] = *(const uint4*)(preW1H + (size_t)c*16 + q*4);
  const float pb0 = pre_b0[c];
  const float pb1 = pre_b1[c];

  for (int nn = 0; nn < 8; ++nn){
    const int n = blockIdx.x * 8 + nn;
    __syncthreads();                 // previous node fully consumed before xdH overwrite
    if (c < 64){
      const float2 v = *(const float2*)(x + (size_t)n*128 + 2*c);
      xdH[c] = pack2(v.x, v.y);
    }
    const int e0 = off[n], e1 = off[n+1];
    float sum = 0.f, sq = 0.f;
    float mn = __builtin_inff(), mx = -__builtin_inff();

    for (int base = e0; base < e1; base += 64){
      const int nv = min(64, e1 - base);
      if (c < nv) sidS[c] = ei[eids[base + c]];
      __syncthreads();

      // software-pipelined staging regs (edge j+1 loaded during edge j compute)
      u32 xs_r = 0, ea_r = 0;
      if (c < 64){
        const float2 v = *(const float2*)(x + (size_t)sidS[0]*128 + 2*c);
        xs_r = pack2(v.x, v.y);
      }
      if (c < 16) ea_r = eaHu[(size_t)base*16 + c];

      for (int j = 0; j < nv; ++j){
        if (c < 64) xsH[c] = xs_r;
        if (c < 16) eaS[c] = ea_r;
        __syncthreads();
        if (j + 1 < nv){
          if (c < 64){
            const float2 v = *(const float2*)(x + (size_t)sidS[j+1]*128 + 2*c);
            xs_r = pack2(v.x, v.y);
          }
          if (c < 16) ea_r = eaHu[(size_t)(base+j+1)*16 + c];
        }

        // layer0: 48 dot2 in 3 independent 16-chains
        float a0 = pb0, a1 = 0.f, a2 = 0.f;
        #pragma unroll
        for (int i = 0; i < 16; ++i){
          a0 = dot2f(xdH[t*16 + i], w0p[i],      a0);
          a1 = dot2f(xsH[t*16 + i], w0p[16 + i], a1);
          a2 = dot2f(eaS[i],        w0p[32 + i], a2);
        }
        const float h = fmaxf(a0 + a1 + a2, 0.f);
        ((u16*)hP)[c] = f2h(h);
        __syncthreads();

        // layer1: 16 dot2 in 2 chains
        float m0 = pb1, m1 = 0.f;
        #pragma unroll
        for (int i = 0; i < 8; ++i){
          m0 = dot2f(hP[t*16 + 2*i],     w1p[2*i],     m0);
          m1 = dot2f(hP[t*16 + 2*i + 1], w1p[2*i + 1], m1);
        }
        const float m = m0 + m1;
        sum += m; sq = fmaf(m, m, sq);
        mn = fminf(mn, m); mx = fmaxf(mx, m);
        __syncthreads();               // protect xsH/eaS/hP before next edge overwrites
      }
    }

    const int deg = e1 - e0;
    const size_t b = (size_t)n * 512;
    agg[b + c]       = sum;
    agg[b + 128 + c] = sq;
    agg[b + 256 + c] = (deg > 0) ? mn : 0.f;
    agg[b + 384 + c] = (deg > 0) ? mx : 0.f;
  }
}

// ======================= node phase: G=12 nodes/block, register-tiled =======================
__global__ __launch_bounds__(128, 2) void k_post(
  const float* __restrict__ x, const float* __restrict__ agg,
  const int* __restrict__ off,
  const float* __restrict__ postW0T, const float* __restrict__ postW1T,
  const float* __restrict__ WlinT,
  const float* __restrict__ post_b0, const float* __restrict__ post_b1,
  const float* __restrict__ b_lin, const float* __restrict__ ln_g,
  const float* __restrict__ ln_b,
  float* __restrict__ out)
{
  const int c = threadIdx.x;
  const int t = c >> 5;
  const int n0 = blockIdx.x * 12;

  __shared__ __align__(16) float aS[12][768];   // [xd | sum | mean | mn | mx | std] x 128
  __shared__ __align__(16) float hpS[12][128];
  __shared__ __align__(16) float vS[12][128];
  __shared__ float s1S[12], s2S[12], muS[12], rsS[12];

  #pragma unroll
  for (int n = 0; n < 12; ++n){
    const size_t nb = (size_t)(n0 + n);
    aS[n][c] = x[nb*128 + c];
    float sum = agg[nb*512 + c];
    float sq  = agg[nb*512 + 128 + c];
    float mnv = agg[nb*512 + 256 + c];
    float mxv = agg[nb*512 + 384 + c];
    int deg = off[n0+n+1] - off[n0+n];
    float denom = fmaxf((float)deg, 1.f);
    float mean = sum / denom;
    float sd = sqrtf(fmaxf(sq/denom - mean*mean, 0.f) + 1e-5f);
    aS[n][128 + c] = sum;  aS[n][256 + c] = mean;
    aS[n][384 + c] = mnv;  aS[n][512 + c] = mxv;  aS[n][640 + c] = sd;
  }
  if (c < 12){
    int deg = off[n0+c+1] - off[n0+c];
    float logd = logf(fmaxf((float)deg, 1.f) + 1.f);
    s1S[c] = logd / ADL; s2S[c] = ADL / logd;
  }
  __syncthreads();

  float acc[12], pa1[12], pa2[12];
  const float pb0 = post_b0[c];
  #pragma unroll
  for (int n = 0; n < 12; ++n){ acc[n] = pb0; pa1[n] = 0.f; pa2[n] = 0.f; }
  const float* Wp = postW0T + (size_t)c * 512;
  #pragma unroll
  for (int k4 = 0; k4 < 8; ++k4){
    float4 w = *(const float4*)(Wp + k4*4);
    #pragma unroll
    for (int n = 0; n < 12; ++n){
      float4 a = *(const float4*)&aS[n][t*32 + k4*4];
      acc[n] = fmaf(a.x, w.x, acc[n]); acc[n] = fmaf(a.y, w.y, acc[n]);
      acc[n] = fmaf(a.z, w.z, acc[n]); acc[n] = fmaf(a.w, w.w, acc[n]);
    }
  }
  for (int a = 0; a < 5; ++a){
    #pragma unroll
    for (int k4 = 0; k4 < 8; ++k4){
      float4 w0v = *(const float4*)(Wp + 32  + a*32 + k4*4);
      float4 w1v = *(const float4*)(Wp + 192 + a*32 + k4*4);
      float4 w2v = *(const float4*)(Wp + 352 + a*32 + k4*4);
      #pragma unroll
      for (int n = 0; n < 12; ++n){
        float4 av = *(const float4*)&aS[n][128 + a*128 + t*32 + k4*4];
        acc[n] = fmaf(av.x, w0v.x, acc[n]); acc[n] = fmaf(av.y, w0v.y, acc[n]);
        acc[n] = fmaf(av.z, w0v.z, acc[n]); acc[n] = fmaf(av.w, w0v.w, acc[n]);
        pa1[n] = fmaf(av.x, w1v.x, pa1[n]); pa1[n] = fmaf(av.y, w1v.y, pa1[n]);
        pa1[n] = fmaf(av.z, w1v.z, pa1[n]); pa1[n] = fmaf(av.w, w1v.w, pa1[n]);
        pa2[n] = fmaf(av.x, w2v.x, pa2[n]); pa2[n] = fmaf(av.y, w2v.y, pa2[n]);
        pa2[n] = fmaf(av.z, w2v.z, pa2[n]); pa2[n] = fmaf(av.w, w2v.w, pa2[n]);
      }
    }
  }
  #pragma unroll
  for (int n = 0; n < 12; ++n)
    hpS[n][c] = fmaxf(acc[n] + s1S[n]*pa1[n] + s2S[n]*pa2[n], 0.f);
  __syncthreads();

  float w1r[32];
  #pragma unroll
  for (int q = 0; q < 8; ++q) *(float4*)&w1r[q*4] = *(const float4*)(postW1T + (size_t)c*32 + q*4);
  float a2[12];
  const float pb1v = post_b1[c];
  #pragma unroll
  for (int n = 0; n < 12; ++n) a2[n] = pb1v;
  #pragma unroll
  for (int g4 = 0; g4 < 8; ++g4){
    #pragma unroll
    for (int n = 0; n < 12; ++n){
      float4 h = *(const float4*)&hpS[n][t*32 + g4*4];
      a2[n] = fmaf(h.x, w1r[g4*4+0], a2[n]); a2[n] = fmaf(h.y, w1r[g4*4+1], a2[n]);
      a2[n] = fmaf(h.z, w1r[g4*4+2], a2[n]); a2[n] = fmaf(h.w, w1r[g4*4+3], a2[n]);
    }
  }
  #pragma unroll
  for (int n = 0; n < 12; ++n) vS[n][c] = a2[n];
  __syncthreads();

  float a3[12];
  const float blv = b_lin[c];
  #pragma unroll
  for (int n = 0; n < 12; ++n) a3[n] = blv;
  const float* Wl = WlinT + (size_t)c * 128;
  #pragma unroll 8
  for (int k4 = 0; k4 < 32; ++k4){
    float4 w = *(const float4*)(Wl + k4*4);
    #pragma unroll
    for (int n = 0; n < 12; ++n){
      float4 v = *(const float4*)&vS[n][k4*4];
      a3[n] = fmaf(v.x, w.x, a3[n]); a3[n] = fmaf(v.y, w.y, a3[n]);
      a3[n] = fmaf(v.z, w.z, a3[n]); a3[n] = fmaf(v.w, w.w, a3[n]);
    }
  }

  #pragma unroll
  for (int n = 0; n < 12; ++n) hpS[n][c] = a3[n];
  __syncthreads();
  {
    const int n = c >> 3, seg = c & 7;
    if (n < 12){
      float ps = 0.f, ps2 = 0.f;
      #pragma unroll
      for (int k = 0; k < 16; ++k){
        float v = hpS[n][seg*16 + k];
        ps += v; ps2 = fmaf(v, v, ps2);
      }
      ps += __shfl_xor(ps, 1); ps2 += __shfl_xor(ps2, 1);
      ps += __shfl_xor(ps, 2); ps2 += __shfl_xor(ps2, 2);
      ps += __shfl_xor(ps, 4); ps2 += __shfl_xor(ps2, 4);
      if (seg == 0){
        float mu = ps * (1.f/128.f);
        float var = fmaxf(ps2 * (1.f/128.f) - mu*mu, 0.f);
        muS[n] = mu; rsS[n] = rsqrtf(var + 1e-5f);
      }
    }
  }
  __syncthreads();
  const float gv = ln_g[c], bv = ln_b[c];
  #pragma unroll
  for (int n = 0; n < 12; ++n){
    float o = aS[n][c] + fmaxf((a3[n] - muS[n])*rsS[n]*gv + bv, 0.f);
    out[(size_t)(n0 + n)*128 + c] = o;
  }
}

// ======================= fallback: proven monolithic kernel (R3, f32) =======================
__global__ __launch_bounds__(128) void k_mono(
  const float* __restrict__ x, const int* __restrict__ ei,
  const float* __restrict__ eattr,
  const float* __restrict__ Wedge, const float* __restrict__ b_edge,
  const float* __restrict__ preW0, const float* __restrict__ pre_b0,
  const float* __restrict__ preW1, const float* __restrict__ pre_b1,
  const float* __restrict__ postW0, const float* __restrict__ post_b0,
  const float* __restrict__ postW1, const float* __restrict__ post_b1,
  const float* __restrict__ Wlin, const float* __restrict__ b_lin,
  const float* __restrict__ ln_g, const float* __restrict__ ln_b,
  const int* __restrict__ off, const int* __restrict__ eids,
  float* __restrict__ out)
{
  const int n = blockIdx.x;
  const int c = threadIdx.x;
  const int t = c >> 5, f = c & 31;
  __shared__ float xdS[128], xsS[128], eaS[32], hS[128];
  __shared__ float aggS[5][128], hpS[128], vS[128], red[4];

  const float xd = x[(size_t)n*128 + c];
  xdS[c] = xd;
  const int e0 = off[n], e1 = off[n+1];
  const int deg = e1 - e0;
  float sum = 0.f, sq = 0.f, mn = __builtin_inff(), mx = -__builtin_inff();
  __syncthreads();

  for (int idx = e0; idx < e1; ++idx){
    const int e = eids[idx];
    const int s = ei[e];
    xsS[c] = x[(size_t)s*128 + c];
    if (c < 32){
      float acc = b_edge[c];
      #pragma unroll
      for (int ii = 0; ii < 16; ++ii) acc = fmaf(eattr[(size_t)e*16 + ii], Wedge[ii*32 + c], acc);
      eaS[c] = acc;
    }
    __syncthreads();
    float acc = pre_b0[c];
    const float* W0 = preW0 + t*3072 + f;
    #pragma unroll 8
    for (int k = 0; k < 32; ++k) acc = fmaf(xdS[t*32+k], W0[k*32], acc);
    #pragma unroll 8
    for (int k = 0; k < 32; ++k) acc = fmaf(xsS[t*32+k], W0[(32+k)*32], acc);
    #pragma unroll 8
    for (int k = 0; k < 32; ++k) acc = fmaf(eaS[k], W0[(64+k)*32], acc);
    hS[c] = fmaxf(acc, 0.f);
    __syncthreads();
    float m = pre_b1[c];
    const float* W1 = preW1 + t*1024 + f;
    #pragma unroll 8
    for (int g = 0; g < 32; ++g) m = fmaf(hS[t*32+g], W1[g*32], m);
    sum += m; sq = fmaf(m, m, sq); mn = fminf(mn, m); mx = fmaxf(mx, m);
    __syncthreads();
  }
  const float d = (float)deg;
  const float denom = fmaxf(d, 1.f);
  const float mean = sum / denom;
  const float sd = sqrtf(fmaxf(sq/denom - mean*mean, 0.f) + 1e-5f);
  const float mnz = (deg > 0) ? mn : 0.f;
  const float mxz = (deg > 0) ? mx : 0.f;
  const float logd = logf(denom + 1.f);
  const float s1 = logd / ADL, s2 = ADL / logd;
  aggS[0][c] = sum; aggS[1][c] = mean; aggS[2][c] = mnz; aggS[3][c] = mxz; aggS[4][c] = sd;
  __syncthreads();
  float acc0 = post_b0[c];
  const float* P0 = postW0 + t*16384 + f;
  #pragma unroll 8
  for (int k = 0; k < 32; ++k) acc0 = fmaf(xdS[t*32+k], P0[k*32], acc0);
  float pa0 = 0.f, pa1 = 0.f, pa2 = 0.f;
  for (int a = 0; a < 5; ++a){
    const float* ag = &aggS[a][t*32];
    const float* Pb = P0 + (32 + a*32)*32;
    #pragma unroll 8
    for (int k = 0; k < 32; ++k){
      const float av = ag[k];
      pa0 = fmaf(av, Pb[k*32], pa0);
      pa1 = fmaf(av, Pb[(160+k)*32], pa1);
      pa2 = fmaf(av, Pb[(320+k)*32], pa2);
    }
  }
  hpS[c] = fmaxf(acc0 + pa0 + s1*pa1 + s2*pa2, 0.f);
  __syncthreads();
  float v = post_b1[c];
  const float* PW1 = postW1 + t*1024 + f;
  #pragma unroll 8
  for (int g = 0; g < 32; ++g) v = fmaf(hpS[t*32+g], PW1[g*32], v);
  vS[c] = v;
  __syncthreads();
  float l = b_lin[c];
  #pragma unroll 8
  for (int k = 0; k < 128; ++k) l = fmaf(vS[k], Wlin[k*128 + c], l);
  float ps = l, ps2 = l*l;
  #pragma unroll
  for (int o = 32; o >= 1; o >>= 1){ ps += __shfl_xor(ps, o); ps2 += __shfl_xor(ps2, o); }
  if ((c & 63) == 0){ red[c>>6] = ps; red[2 + (c>>6)] = ps2; }
  __syncthreads();
  const float mu = (red[0] + red[1]) * (1.f/128.f);
  const float var = fmaxf((red[2] + red[3]) * (1.f/128.f) - mu*mu, 0.f);
  const float rstd = rsqrtf(var + 1e-5f);
  out[(size_t)n*128 + c] = xd + fmaxf((l - mu)*rstd*ln_g[c] + ln_b[c], 0.f);
}

// ======================= launch =======================
extern "C" void kernel_launch(void* const* d_in, const int* in_sizes, int n_in,
                              void* d_out, int out_size, void* d_ws, size_t ws_size,
                              hipStream_t stream){
  const float* x       = (const float*)d_in[0];
  const int*   ei      = (const int*)d_in[1];
  const float* eattr   = (const float*)d_in[2];
  const float* Wedge   = (const float*)d_in[3];
  const float* b_edge  = (const float*)d_in[4];
  const float* preW0   = (const float*)d_in[5];
  const float* pre_b0  = (const float*)d_in[6];
  const float* preW1   = (const float*)d_in[7];
  const float* pre_b1  = (const float*)d_in[8];
  const float* postW0  = (const float*)d_in[9];
  const float* post_b0 = (const float*)d_in[10];
  const float* postW1  = (const float*)d_in[11];
  const float* post_b1 = (const float*)d_in[12];
  const float* Wlin    = (const float*)d_in[13];
  const float* b_lin   = (const float*)d_in[14];
  const float* ln_g    = (const float*)d_in[15];
  const float* ln_b    = (const float*)d_in[16];

  char* ws = (char*)d_ws;
  size_t o = 0;
  auto alloc = [&](size_t bytes)->char*{
    char* p = ws + o; o = (o + bytes + 255) & ~((size_t)255); return p;
  };
  int* off    = (int*)alloc((NN + 1) * 4);
  int* cnt    = (int*)alloc(NN * 4);
  int* cursor = (int*)alloc(NN * 4);
  int* eids   = (int*)alloc(NE * 4);
  u32* preW0H  = (u32*)alloc(6144 * 4);
  u32* preW1H  = (u32*)alloc(2048 * 4);
  float* postW0T = (float*)alloc(65536 * 4);
  float* postW1T = (float*)alloc(4096 * 4);
  float* WlinT   = (float*)alloc(16384 * 4);
  u16* eaH     = (u16*)alloc((size_t)NE * 32 * 2);
  float* agg   = (float*)alloc((size_t)NN * 512 * 4);
  const size_t need = o;

  // CSR build (both paths)
  k_zero<<<(NN + 255)/256, 256, 0, stream>>>(cnt, cursor);
  k_hist<<<(NE + 255)/256, 256, 0, stream>>>(ei, cnt);
  k_scan<<<1, 1024, 0, stream>>>(cnt, off);
  k_scatter<<<(NE + 255)/256, 256, 0, stream>>>(ei, off, cursor, eids);

  if (ws_size < need){
    k_mono<<<NN, 128, 0, stream>>>(x, ei, eattr, Wedge, b_edge,
                                   preW0, pre_b0, preW1, pre_b1,
                                   postW0, post_b0, postW1, post_b1,
                                   Wlin, b_lin, ln_g, ln_b,
                                   off, eids, (float*)d_out);
    return;
  }

  k_prep<<<256, 256, 0, stream>>>(preW0, preW1, postW0, postW1, Wlin,
                                  preW0H, preW1H, postW0T, postW1T, WlinT);
  k_ea<<<(NE + 7)/8, 256, 0, stream>>>(eattr, Wedge, b_edge, eids, eaH);
  k_edge3<<<NN/8, 128, 0, stream>>>(x, ei, (const u32*)eaH, preW0H, preW1H,
                                    pre_b0, pre_b1, off, eids, agg);
  k_post<<<NN/12, 128, 0, stream>>>(x, agg, off, postW0T, postW1T, WlinT,
                                    post_b0, post_b1, b_lin, ln_g, ln_b,
                                    (float*)d_out);
}